// Round 6
// baseline (149.332 us; speedup 1.0000x reference)
//
#include <hip/hip_runtime.h>

#define BB 4
#define HH 384
#define WW 384
#define HWSZ (HH * WW)
#define KK 64
#define TSH 32
#define TSW 64
#define TPB_X 6                  // tiles across (384/64)
#define TPB_Y 12                 // tiles down  (384/32)
#define NT (TPB_X * TPB_Y)       // 72 tiles per batch
#define MAXR 1024                // max roots per 32x64 tile (worst case)
#define NB 576                   // histogram buckets: 147456 >> 8
#define NS 8                     // root-cache slots per accum block
#define INFI 0x7FFFFFFF
#define INFV 0x7F7F7F7F
#define DTOT (BB * KK * (WW + HH))   // dcol+drow ints = 196608
#define DCHUNK 683                   // ceil(DTOT / (BB*NT))

// ---- union-find on GLOBAL memory (bridge/accum; path halving, monotone links)
__device__ __forceinline__ int ufind(int* par, int i) {
    while (true) {
        int p = par[i];
        if (p == i) return i;
        int gp = par[p];
        if (gp == p) return p;
        par[i] = gp;
        i = gp;
    }
}

__device__ __forceinline__ void uunion(int* par, int a, int b) {
    while (true) {
        a = ufind(par, a);
        b = ufind(par, b);
        if (a == b) return;
        if (a > b) { int t = a; a = b; b = t; }
        int old = atomicCAS(&par[b], b, a);
        if (old == b) return;
        b = old;
    }
}

// ---- union-find on LDS
__device__ __forceinline__ int lfind(int* par, int i) {
    while (true) {
        int p = par[i];
        if (p == i) return i;
        int gp = par[p];
        if (gp == p) return p;
        par[i] = gp;
        i = gp;
    }
}

__device__ __forceinline__ void luni(int* par, int a, int b) {
    while (true) {
        a = lfind(par, a);
        b = lfind(par, b);
        if (a == b) return;
        if (a > b) { int t = a; a = b; b = t; }
        int old = atomicCAS(&par[b], b, a);
        if (old == b) return;
        b = old;
    }
}

__device__ __forceinline__ int lookup_k(const int* sids, int r) {
    int lo = 0, hi = KK - 1;
    while (lo <= hi) {
        int mid = (lo + hi) >> 1;
        int v = sids[mid];
        if (v == r) return mid;
        if (v < r) lo = mid + 1; else hi = mid - 1;
    }
    return -1;
}

// 1. fused: dcol/drow init + mask + run-leader CC + leader flatten + par write
//    + per-tile root list (unconditional writes -> no memsets needed anywhere)
__global__ __launch_bounds__(256) void cc_tile_k(const float* __restrict__ x,
                                                 int* __restrict__ parent,
                                                 int* __restrict__ tileCnt,
                                                 int* __restrict__ tileList,
                                                 int* __restrict__ dinit) {
    __shared__ int lp[TSH * TSW];               // 8 KB
    __shared__ unsigned short leadL[MAXR];      // 2 KB
    __shared__ unsigned short rootL[MAXR];      // 2 KB
    __shared__ int nLead, nRoot;
    int blk = blockIdx.x;
    int b = blk / NT, t2 = blk - b * NT;
    int th0 = (t2 / TPB_X) * TSH, tw0 = (t2 % TPB_X) * TSW;
    int* par = parent + b * HWSZ;
    int tid = threadIdx.x, ln = tid & 63, wv = tid >> 6;

    // dcol/drow init: this block's chunk of the 0x7F pattern
    {
        int beg = blk * DCHUNK;
        int end = beg + DCHUNK; if (end > DTOT) end = DTOT;
        for (int i = beg + tid; i < end; i += 256) dinit[i] = INFV;
    }
    if (tid == 0) { nLead = 0; nRoot = 0; }
    __syncthreads();

    // pass 1: per-row horizontal run-leaders via ballot; collect leader list
    for (int r = wv; r < TSH; r += 4) {
        int h = th0 + r, w = tw0 + ln;
        int gi = (b * HH + h) * WW + w;
        float2 v = *(const float2*)(x + 2 * gi);
        bool m = (v.x > 0.4f) || (v.y > 0.4f);
        unsigned long long mb = __ballot(m);
        unsigned long long below = (~mb) & ((1ull << ln) - 1ull);
        int s = below ? (64 - __clzll(below)) : 0;
        int l = r * 64 + ln;
        lp[l] = m ? (r * 64 + s) : -1;
        if (m && s == ln) {                      // run leader
            int i2 = atomicAdd(&nLead, 1);
            leadL[i2] = (unsigned short)l;
        }
    }
    __syncthreads();
    // pass 2: vertical unions, one per overlap-run (dedup via ballot)
    for (int r = wv; r < TSH; r += 4) {
        if (r == 0) continue;                    // wave-uniform
        int l = r * 64 + ln;
        bool ov = (lp[l] >= 0) && (lp[l - 64] >= 0);
        unsigned long long ob = __ballot(ov);
        if (ov && (ln == 0 || !((ob >> (ln - 1)) & 1ull)))
            luni(lp, l, l - 64);
    }
    __syncthreads();
    // pass 2.5: flatten leaders exactly; collect roots
    int nl = nLead;
    for (int i = tid; i < nl; i += 256) {
        int l = leadL[i];
        int r = lfind(lp, l);
        if (r != l) lp[l] = r;                   // monotone write, race-benign
        else { int j = atomicAdd(&nRoot, 1); rootL[j] = (unsigned short)l; }
    }
    __syncthreads();
    // pass 3: loop-free root per pixel (lp[l] -> leader, lp[leader] -> root)
    for (int l = tid; l < TSH * TSW; l += 256) {
        int v = lp[l];
        int h = th0 + (l >> 6), w = tw0 + (l & 63);
        int res = -1;
        if (v >= 0) {
            int r = lp[v];
            res = (th0 + (r >> 6)) * WW + (tw0 + (r & 63));
        }
        par[h * WW + w] = res;
    }
    int nr = nRoot;
    for (int i = tid; i < nr; i += 256) {
        int l = rootL[i];
        tileList[blk * MAXR + i] = (th0 + (l >> 6)) * WW + (tw0 + (l & 63));
    }
    if (tid == 0) tileCnt[blk] = nr;
}

// 2. fused bridge + select: one block per batch
__global__ __launch_bounds__(256) void select_k(const int* __restrict__ tileCnt,
                                                const int* __restrict__ tileList,
                                                int* __restrict__ parent,
                                                int* __restrict__ ids) {
    int b = blockIdx.x, tid = threadIdx.x;
    int* par = parent + b * HWSZ;

    // ---- bridge: cross-tile boundary unions for this batch
    const int NEV = 5 * WW;                      // vertical boundaries w=63+64*line
    const int NE = NEV + 11 * WW;                // + horizontal h=31+32*line
    for (int e = tid; e < NE; e += 256) {
        int p, q;
        if (e < NEV) {
            int line = e / WW, pos = e - line * WW;
            p = pos * WW + (63 + 64 * line); q = p + 1;
        } else {
            int eh = e - NEV;
            int line = eh / WW, pos = eh - line * WW;
            p = (31 + 32 * line) * WW + pos; q = p + WW;
        }
        if (par[p] >= 0 && par[q] >= 0) uunion(par, p, q);  // sign stable; CAS coherent
    }
    __syncthreads();

    // ---- selection: KK smallest surviving roots, sorted
    __shared__ int pf[NT + 1];
    __shared__ int hist[NB];
    __shared__ int cand[512];
    __shared__ int Bsh, cnt;
    if (tid < NT) pf[tid + 1] = tileCnt[b * NT + tid];
    if (tid == 0) pf[0] = 0;
    for (int i = tid; i < NB; i += 256) hist[i] = 0;
    if (tid < KK) ids[b * KK + tid] = INFI;
    if (tid == 0) cnt = 0;
    __syncthreads();
    if (tid == 0) for (int i = 0; i < NT; ++i) pf[i + 1] += pf[i];
    __syncthreads();
    int total = pf[NT];
    for (int j = tid; j < total; j += 256) {
        int lo = 0, hi = NT;
        while (lo + 1 < hi) { int mid = (lo + hi) >> 1; if (pf[mid] <= j) lo = mid; else hi = mid; }
        int v = tileList[(b * NT + lo) * MAXR + (j - pf[lo])];
        // agent-scope load: must see this block's own bridge CAS writes (L1 bypass)
        int pv = __hip_atomic_load(&par[v], __ATOMIC_RELAXED, __HIP_MEMORY_SCOPE_AGENT);
        if (pv == v) atomicAdd(&hist[v >> 8], 1);
    }
    __syncthreads();
    if (tid == 0) {
        int valid = 0;
        for (int i = 0; i < NB; ++i) valid += hist[i];
        int target = valid < KK ? valid : KK;
        int Bv = -1;
        if (target > 0) {
            int c = 0;
            for (int i = 0; i < NB; ++i) { c += hist[i]; if (c >= target) { Bv = i; break; } }
        }
        Bsh = Bv;
    }
    __syncthreads();
    int Bv = Bsh;
    if (Bv >= 0) {
        for (int j = tid; j < total; j += 256) {
            int lo = 0, hi = NT;
            while (lo + 1 < hi) { int mid = (lo + hi) >> 1; if (pf[mid] <= j) lo = mid; else hi = mid; }
            int v = tileList[(b * NT + lo) * MAXR + (j - pf[lo])];
            if ((v >> 8) <= Bv) {
                int pv = __hip_atomic_load(&par[v], __ATOMIC_RELAXED, __HIP_MEMORY_SCOPE_AGENT);
                if (pv == v) { int pos = atomicAdd(&cnt, 1); if (pos < 512) cand[pos] = v; }
            }
        }
    }
    __syncthreads();
    int m2 = cnt < 512 ? cnt : 512;
    for (int i = tid; i < m2; i += 256) {
        int v = cand[i];
        int r = 0;
        for (int j = 0; j < m2; ++j) r += (cand[j] < v);
        if (r < KK) ids[b * KK + r] = v;
    }
}

// 3. per 32x64 sub-tile: LDS-aggregated dilated col/row mins, memoized root, flush
__global__ __launch_bounds__(256) void accum_k(const int* __restrict__ parent,
                                               const int* __restrict__ ids,
                                               int* __restrict__ dcol,
                                               int* __restrict__ drow) {
    __shared__ int sids[KK];
    __shared__ unsigned long long table[NS];     // (root+1)<<32 | (k+2); 0 = empty
    __shared__ int scol[NS][TSW];
    __shared__ int srow[NS][TSH];
    int blk = blockIdx.x;
    int b = blk / NT, t2 = blk - b * NT;
    int th0 = (t2 / TPB_X) * TSH, tw0 = (t2 % TPB_X) * TSW;
    const int* par = parent + b * HWSZ;
    int tid = threadIdx.x;

    if (tid < KK) sids[tid] = ids[b * KK + tid];
    if (tid < NS) table[tid] = 0ull;
    for (int i = tid; i < NS * TSW; i += 256) ((int*)scol)[i] = INFI;
    for (int i = tid; i < NS * TSH; i += 256) ((int*)srow)[i] = INFI;
    __syncthreads();

    int lastpv = -2, lastk = -1, lastslot = -1;
    for (int c = 0; c < 2; ++c) {
        int base = (tid + c * 256) * 4;          // 0..2044
        int lh = base >> 6, lw = base & 63;
        int h = th0 + lh, w0 = tw0 + lw;
        int4 pr = *(const int4*)&par[h * WW + w0];
        int fh = (h >= 2) ? h - 2 : h;
        #pragma unroll
        for (int e = 0; e < 4; ++e) {
            int pv = (e == 0) ? pr.x : (e == 1) ? pr.y : (e == 2) ? pr.z : pr.w;
            if (pv < 0) continue;
            int k, slot;
            if (pv == lastpv) { k = lastk; slot = lastslot; }
            else {
                int r = pv, nx;
                while ((nx = par[r]) != r) r = nx;   // post-bridge chase (short)
                k = -2; slot = -1;
                for (int i2 = 0; i2 < NS; ++i2) {
                    unsigned long long ev = table[i2];
                    if (ev == 0ull) {
                        if (k == -2) k = lookup_k(sids, r);
                        unsigned long long me =
                            ((unsigned long long)(unsigned)(r + 1) << 32) | (unsigned)(k + 2);
                        unsigned long long old = atomicCAS(&table[i2], 0ull, me);
                        if (old == 0ull) { slot = i2; break; }
                        ev = old;
                    }
                    if ((unsigned)(ev >> 32) == (unsigned)(r + 1)) {
                        k = (int)(unsigned)(ev & 0xffffffffull) - 2;
                        slot = i2; break;
                    }
                }
                if (slot < 0 && k == -2) k = lookup_k(sids, r);
                lastpv = pv; lastk = k; lastslot = slot;
            }
            if (k < 0) continue;
            int w = w0 + e;
            int fw = (w >= 2) ? w - 2 : w;
            if (slot >= 0) {
                atomicMin(&scol[slot][lw + e], fh);
                atomicMin(&srow[slot][lh], fw);
            } else {
                atomicMin(&dcol[(b * KK + k) * WW + w], fh);
                atomicMin(&drow[(b * KK + k) * HH + h], fw);
            }
        }
    }
    __syncthreads();
    for (int i = tid; i < NS * TSW; i += 256) {
        int s = i >> 6, pos = i & 63;
        unsigned long long ev = table[s];
        if (ev == 0ull) continue;
        int k = (int)(unsigned)(ev & 0xffffffffull) - 2;
        if (k < 0) continue;
        int v = scol[s][pos];
        if (v < INFI) atomicMin(&dcol[(b * KK + k) * WW + tw0 + pos], v);
        if (pos < TSH) {
            int v2 = srow[s][pos];
            if (v2 < INFI) atomicMin(&drow[(b * KK + k) * HH + th0 + pos], v2);
        }
    }
}

// 4. one block per (b,k): argmax!=0 semantics, reduce, emit bbox
__global__ __launch_bounds__(384) void bbox_k(const int* __restrict__ dcol,
                                              const int* __restrict__ drow,
                                              int* __restrict__ out) {
    int bk = blockIdx.x;
    int t = threadIdx.x;                         // 0..383 == WW == HH
    const int* dc = dcol + bk * WW;
    const int* dr = drow + bk * HH;

    int hm = dc[t];
    if (t >= 2) hm = min(hm, dc[t - 2]);
    if (t + 2 < WW) hm = min(hm, dc[t + 2]);
    bool mc = (hm < INFV) && (hm >= 1);
    int cmin = mc ? t : INFI;
    int cmax = mc ? t : -1;

    int wm = dr[t];
    if (t >= 2) wm = min(wm, dr[t - 2]);
    if (t + 2 < HH) wm = min(wm, dr[t + 2]);
    bool mr = (wm < INFV) && (wm >= 1);
    int rmin = mr ? t : INFI;
    int rmax = mr ? t : -1;

    for (int o = 1; o < 64; o <<= 1) {
        cmin = min(cmin, __shfl_xor(cmin, o));
        cmax = max(cmax, __shfl_xor(cmax, o));
        rmin = min(rmin, __shfl_xor(rmin, o));
        rmax = max(rmax, __shfl_xor(rmax, o));
    }
    __shared__ int s[4][6];
    int wv = t >> 6;
    if ((t & 63) == 0) { s[0][wv] = cmin; s[1][wv] = cmax; s[2][wv] = rmin; s[3][wv] = rmax; }
    __syncthreads();
    if (t == 0) {
        int CMin = s[0][0], CMax = s[1][0], RMin = s[2][0], RMax = s[3][0];
        for (int i = 1; i < 6; ++i) {
            CMin = min(CMin, s[0][i]); CMax = max(CMax, s[1][i]);
            RMin = min(RMin, s[2][i]); RMax = max(RMax, s[3][i]);
        }
        int x2, y2, wext, hext;
        if (RMax >= 0) { x2 = RMin; wext = RMax - RMin; } else { x2 = 0; wext = 1; }
        if (CMax >= 0) { y2 = CMin; hext = CMax - CMin; } else { y2 = 0; hext = 1; }
        out[bk * 4 + 0] = x2;
        out[bk * 4 + 1] = y2;
        out[bk * 4 + 2] = wext;
        out[bk * 4 + 3] = hext;
    }
}

extern "C" void kernel_launch(void* const* d_in, const int* in_sizes, int n_in,
                              void* d_out, int out_size, void* d_ws, size_t ws_size,
                              hipStream_t stream) {
    const float* x = (const float*)d_in[0];
    int* out = (int*)d_out;

    int* parent   = (int*)d_ws;                      // BB*HWSZ
    int* tileCnt  = parent + BB * HWSZ;              // BB*NT
    int* tileList = tileCnt + BB * NT;               // BB*NT*MAXR
    int* ids      = tileList + BB * NT * MAXR;       // BB*KK
    int* dcol     = ids + BB * KK;                   // BB*KK*WW
    int* drow     = dcol + BB * KK * WW;             // BB*KK*HH (contiguous)

    cc_tile_k<<<BB * NT, 256, 0, stream>>>(x, parent, tileCnt, tileList, dcol);
    select_k<<<BB, 256, 0, stream>>>(tileCnt, tileList, parent, ids);
    accum_k<<<BB * NT, 256, 0, stream>>>(parent, ids, dcol, drow);
    bbox_k<<<BB * KK, 384, 0, stream>>>(dcol, drow, out);
}

// Round 7
// 91.716 us; speedup vs baseline: 1.6282x; 1.6282x over previous
//
#include <hip/hip_runtime.h>

#define BB 4
#define HH 384
#define WW 384
#define HWSZ (HH * WW)
#define KK 64
#define TSH 32
#define TSW 64
#define TPB_X 6                  // tiles across (384/64)
#define TPB_Y 12                 // tiles down  (384/32)
#define NT (TPB_X * TPB_Y)       // 72 tiles per batch
#define MAXR 1024                // max roots per 32x64 tile (worst case)
#define NS 8                     // root-cache slots per accum block
#define CANDC 2048
#define INFI 0x7FFFFFFF
#define INFV 0x7F7F7F7F
#define DTOT (BB * KK * (WW + HH))   // dcol+drow ints = 196608
#define DCHUNK 683                   // ceil(DTOT / (BB*NT))

// ---- agent-coherent union-find on GLOBAL memory (bridge): L2-coherent loads
__device__ __forceinline__ int afind(int* par, int i) {
    while (true) {
        int p = __hip_atomic_load(&par[i], __ATOMIC_RELAXED, __HIP_MEMORY_SCOPE_AGENT);
        if (p == i) return i;
        i = p;
    }
}

__device__ __forceinline__ void auni(int* par, int a, int b) {
    while (true) {
        a = afind(par, a);
        b = afind(par, b);
        if (a == b) return;
        if (a > b) { int t = a; a = b; b = t; }
        int old = atomicCAS(&par[b], b, a);
        if (old == b) return;
        b = old;
    }
}

// ---- union-find on LDS
__device__ __forceinline__ int lfind(int* par, int i) {
    while (true) {
        int p = par[i];
        if (p == i) return i;
        int gp = par[p];
        if (gp == p) return p;
        par[i] = gp;
        i = gp;
    }
}

__device__ __forceinline__ void luni(int* par, int a, int b) {
    while (true) {
        a = lfind(par, a);
        b = lfind(par, b);
        if (a == b) return;
        if (a > b) { int t = a; a = b; b = t; }
        int old = atomicCAS(&par[b], b, a);
        if (old == b) return;
        b = old;
    }
}

__device__ __forceinline__ int lookup_k(const int* sids, int r) {
    int lo = 0, hi = KK - 1;
    while (lo <= hi) {
        int mid = (lo + hi) >> 1;
        int v = sids[mid];
        if (v == r) return mid;
        if (v < r) lo = mid + 1; else hi = mid - 1;
    }
    return -1;
}

// 1. fused: dcol/drow init + mask + run-leader CC + leader flatten + par write
//    + per-tile root list (unconditional writes -> no memsets needed anywhere)
__global__ __launch_bounds__(256) void cc_tile_k(const float* __restrict__ x,
                                                 int* __restrict__ parent,
                                                 int* __restrict__ tileCnt,
                                                 int* __restrict__ tileList,
                                                 int* __restrict__ dinit) {
    __shared__ int lp[TSH * TSW];               // 8 KB
    __shared__ unsigned short leadL[MAXR];      // 2 KB
    __shared__ unsigned short rootL[MAXR];      // 2 KB
    __shared__ int nLead, nRoot;
    int blk = blockIdx.x;
    int b = blk / NT, t2 = blk - b * NT;
    int th0 = (t2 / TPB_X) * TSH, tw0 = (t2 % TPB_X) * TSW;
    int* par = parent + b * HWSZ;
    int tid = threadIdx.x, ln = tid & 63, wv = tid >> 6;

    // dcol/drow init: this block's chunk of the 0x7F pattern
    {
        int beg = blk * DCHUNK;
        int end = beg + DCHUNK; if (end > DTOT) end = DTOT;
        for (int i = beg + tid; i < end; i += 256) dinit[i] = INFV;
    }
    if (tid == 0) { nLead = 0; nRoot = 0; }
    __syncthreads();

    // pass 1: per-row horizontal run-leaders via ballot; collect leader list
    for (int r = wv; r < TSH; r += 4) {
        int h = th0 + r, w = tw0 + ln;
        int gi = (b * HH + h) * WW + w;
        float2 v = *(const float2*)(x + 2 * gi);
        bool m = (v.x > 0.4f) || (v.y > 0.4f);
        unsigned long long mb = __ballot(m);
        unsigned long long below = (~mb) & ((1ull << ln) - 1ull);
        int s = below ? (64 - __clzll(below)) : 0;
        int l = r * 64 + ln;
        lp[l] = m ? (r * 64 + s) : -1;
        if (m && s == ln) {                      // run leader
            int i2 = atomicAdd(&nLead, 1);
            leadL[i2] = (unsigned short)l;
        }
    }
    __syncthreads();
    // pass 2: vertical unions, one per overlap-run (dedup via ballot)
    for (int r = wv; r < TSH; r += 4) {
        if (r == 0) continue;                    // wave-uniform
        int l = r * 64 + ln;
        bool ov = (lp[l] >= 0) && (lp[l - 64] >= 0);
        unsigned long long ob = __ballot(ov);
        if (ov && (ln == 0 || !((ob >> (ln - 1)) & 1ull)))
            luni(lp, l, l - 64);
    }
    __syncthreads();
    // pass 2.5: flatten leaders exactly; collect roots
    int nl = nLead;
    for (int i = tid; i < nl; i += 256) {
        int l = leadL[i];
        int r = lfind(lp, l);
        if (r != l) lp[l] = r;                   // monotone write, race-benign
        else { int j = atomicAdd(&nRoot, 1); rootL[j] = (unsigned short)l; }
    }
    __syncthreads();
    // pass 3: loop-free root per pixel (lp[l] -> leader, lp[leader] -> root)
    for (int l = tid; l < TSH * TSW; l += 256) {
        int v = lp[l];
        int h = th0 + (l >> 6), w = tw0 + (l & 63);
        int res = -1;
        if (v >= 0) {
            int r = lp[v];
            res = (th0 + (r >> 6)) * WW + (tw0 + (r & 63));
        }
        par[h * WW + w] = res;
    }
    int nr = nRoot;
    for (int i = tid; i < nr; i += 256) {
        int l = rootL[i];
        tileList[blk * MAXR + i] = (th0 + (l >> 6)) * WW + (tw0 + (l & 63));
    }
    if (tid == 0) tileCnt[blk] = nr;
}

// 2. cross-tile boundary unions, 1 edge/thread, agent-coherent finds
__global__ void bridge_k(int* __restrict__ parent) {
    const int NEV = 5 * WW;                      // vertical boundaries w=63+64*line
    const int NE = NEV + 11 * WW;                // + horizontal h=31+32*line
    int i = blockIdx.x * 256 + threadIdx.x;
    if (i >= BB * NE) return;
    int b = i / NE, e = i - b * NE;
    int* par = parent + b * HWSZ;
    int p, q;
    if (e < NEV) {
        int line = e / WW, pos = e - line * WW;
        p = pos * WW + (63 + 64 * line); q = p + 1;
    } else {
        int eh = e - NEV;
        int line = eh / WW, pos = eh - line * WW;
        p = (31 + 32 * line) * WW + pos; q = p + WW;
    }
    if (par[p] >= 0 && par[q] >= 0) auni(par, p, q);   // mask sign is stable
}

// 3. per batch: collect surviving roots, rank, emit sorted first KK
__global__ __launch_bounds__(256) void select_k(const int* __restrict__ tileCnt,
                                                const int* __restrict__ tileList,
                                                const int* __restrict__ parent,
                                                int* __restrict__ ids) {
    int b = blockIdx.x, tid = threadIdx.x;
    const int* par = parent + b * HWSZ;
    __shared__ int pf[NT + 1];
    __shared__ int cand[CANDC];
    __shared__ int cnt;
    if (tid < NT) pf[tid + 1] = tileCnt[b * NT + tid];
    if (tid == 0) { pf[0] = 0; cnt = 0; }
    if (tid < KK) ids[b * KK + tid] = INFI;
    __syncthreads();
    if (tid == 0) for (int i = 0; i < NT; ++i) pf[i + 1] += pf[i];
    __syncthreads();
    int total = pf[NT];
    for (int j = tid; j < total; j += 256) {
        int lo = 0, hi = NT;
        while (lo + 1 < hi) { int mid = (lo + hi) >> 1; if (pf[mid] <= j) lo = mid; else hi = mid; }
        int v = tileList[(b * NT + lo) * MAXR + (j - pf[lo])];
        if (par[v] == v) {                       // coherent: kernel boundary after bridge
            int pos = atomicAdd(&cnt, 1);
            if (pos < CANDC) cand[pos] = v;
        }
    }
    __syncthreads();
    int m2 = cnt < CANDC ? cnt : CANDC;
    for (int i = tid; i < m2; i += 256) {
        int v = cand[i];
        int r = 0;
        for (int j = 0; j < m2; ++j) r += (cand[j] < v);
        if (r < KK) ids[b * KK + r] = v;
    }
}

// 4. per 32x64 sub-tile: LDS-aggregated dilated col/row mins, memoized root, flush
__global__ __launch_bounds__(256) void accum_k(const int* __restrict__ parent,
                                               const int* __restrict__ ids,
                                               int* __restrict__ dcol,
                                               int* __restrict__ drow) {
    __shared__ int sids[KK];
    __shared__ unsigned long long table[NS];     // (root+1)<<32 | (k+2); 0 = empty
    __shared__ int scol[NS][TSW];
    __shared__ int srow[NS][TSH];
    int blk = blockIdx.x;
    int b = blk / NT, t2 = blk - b * NT;
    int th0 = (t2 / TPB_X) * TSH, tw0 = (t2 % TPB_X) * TSW;
    const int* par = parent + b * HWSZ;
    int tid = threadIdx.x;

    if (tid < KK) sids[tid] = ids[b * KK + tid];
    if (tid < NS) table[tid] = 0ull;
    for (int i = tid; i < NS * TSW; i += 256) ((int*)scol)[i] = INFI;
    for (int i = tid; i < NS * TSH; i += 256) ((int*)srow)[i] = INFI;
    __syncthreads();

    int lastpv = -2, lastk = -1, lastslot = -1;
    for (int c = 0; c < 2; ++c) {
        int base = (tid + c * 256) * 4;          // 0..2044
        int lh = base >> 6, lw = base & 63;
        int h = th0 + lh, w0 = tw0 + lw;
        int4 pr = *(const int4*)&par[h * WW + w0];
        int fh = (h >= 2) ? h - 2 : h;
        #pragma unroll
        for (int e = 0; e < 4; ++e) {
            int pv = (e == 0) ? pr.x : (e == 1) ? pr.y : (e == 2) ? pr.z : pr.w;
            if (pv < 0) continue;
            int k, slot;
            if (pv == lastpv) { k = lastk; slot = lastslot; }
            else {
                int r = pv, nx;
                while ((nx = par[r]) != r) r = nx;   // post-bridge chase (short)
                k = -2; slot = -1;
                for (int i2 = 0; i2 < NS; ++i2) {
                    unsigned long long ev = table[i2];
                    if (ev == 0ull) {
                        if (k == -2) k = lookup_k(sids, r);
                        unsigned long long me =
                            ((unsigned long long)(unsigned)(r + 1) << 32) | (unsigned)(k + 2);
                        unsigned long long old = atomicCAS(&table[i2], 0ull, me);
                        if (old == 0ull) { slot = i2; break; }
                        ev = old;
                    }
                    if ((unsigned)(ev >> 32) == (unsigned)(r + 1)) {
                        k = (int)(unsigned)(ev & 0xffffffffull) - 2;
                        slot = i2; break;
                    }
                }
                if (slot < 0 && k == -2) k = lookup_k(sids, r);
                lastpv = pv; lastk = k; lastslot = slot;
            }
            if (k < 0) continue;
            int w = w0 + e;
            int fw = (w >= 2) ? w - 2 : w;
            if (slot >= 0) {
                atomicMin(&scol[slot][lw + e], fh);
                atomicMin(&srow[slot][lh], fw);
            } else {
                atomicMin(&dcol[(b * KK + k) * WW + w], fh);
                atomicMin(&drow[(b * KK + k) * HH + h], fw);
            }
        }
    }
    __syncthreads();
    for (int i = tid; i < NS * TSW; i += 256) {
        int s = i >> 6, pos = i & 63;
        unsigned long long ev = table[s];
        if (ev == 0ull) continue;
        int k = (int)(unsigned)(ev & 0xffffffffull) - 2;
        if (k < 0) continue;
        int v = scol[s][pos];
        if (v < INFI) atomicMin(&dcol[(b * KK + k) * WW + tw0 + pos], v);
        if (pos < TSH) {
            int v2 = srow[s][pos];
            if (v2 < INFI) atomicMin(&drow[(b * KK + k) * HH + th0 + pos], v2);
        }
    }
}

// 5. one block per (b,k): argmax!=0 semantics, reduce, emit bbox
__global__ __launch_bounds__(384) void bbox_k(const int* __restrict__ dcol,
                                              const int* __restrict__ drow,
                                              int* __restrict__ out) {
    int bk = blockIdx.x;
    int t = threadIdx.x;                         // 0..383 == WW == HH
    const int* dc = dcol + bk * WW;
    const int* dr = drow + bk * HH;

    int hm = dc[t];
    if (t >= 2) hm = min(hm, dc[t - 2]);
    if (t + 2 < WW) hm = min(hm, dc[t + 2]);
    bool mc = (hm < INFV) && (hm >= 1);
    int cmin = mc ? t : INFI;
    int cmax = mc ? t : -1;

    int wm = dr[t];
    if (t >= 2) wm = min(wm, dr[t - 2]);
    if (t + 2 < HH) wm = min(wm, dr[t + 2]);
    bool mr = (wm < INFV) && (wm >= 1);
    int rmin = mr ? t : INFI;
    int rmax = mr ? t : -1;

    for (int o = 1; o < 64; o <<= 1) {
        cmin = min(cmin, __shfl_xor(cmin, o));
        cmax = max(cmax, __shfl_xor(cmax, o));
        rmin = min(rmin, __shfl_xor(rmin, o));
        rmax = max(rmax, __shfl_xor(rmax, o));
    }
    __shared__ int s[4][6];
    int wv = t >> 6;
    if ((t & 63) == 0) { s[0][wv] = cmin; s[1][wv] = cmax; s[2][wv] = rmin; s[3][wv] = rmax; }
    __syncthreads();
    if (t == 0) {
        int CMin = s[0][0], CMax = s[1][0], RMin = s[2][0], RMax = s[3][0];
        for (int i = 1; i < 6; ++i) {
            CMin = min(CMin, s[0][i]); CMax = max(CMax, s[1][i]);
            RMin = min(RMin, s[2][i]); RMax = max(RMax, s[3][i]);
        }
        int x2, y2, wext, hext;
        if (RMax >= 0) { x2 = RMin; wext = RMax - RMin; } else { x2 = 0; wext = 1; }
        if (CMax >= 0) { y2 = CMin; hext = CMax - CMin; } else { y2 = 0; hext = 1; }
        out[bk * 4 + 0] = x2;
        out[bk * 4 + 1] = y2;
        out[bk * 4 + 2] = wext;
        out[bk * 4 + 3] = hext;
    }
}

extern "C" void kernel_launch(void* const* d_in, const int* in_sizes, int n_in,
                              void* d_out, int out_size, void* d_ws, size_t ws_size,
                              hipStream_t stream) {
    const float* x = (const float*)d_in[0];
    int* out = (int*)d_out;

    int* parent   = (int*)d_ws;                      // BB*HWSZ
    int* tileCnt  = parent + BB * HWSZ;              // BB*NT
    int* tileList = tileCnt + BB * NT;               // BB*NT*MAXR
    int* ids      = tileList + BB * NT * MAXR;       // BB*KK
    int* dcol     = ids + BB * KK;                   // BB*KK*WW
    int* drow     = dcol + BB * KK * WW;             // BB*KK*HH (contiguous)

    const int NE4 = BB * (16 * WW);                  // 24576 edges total

    cc_tile_k<<<BB * NT, 256, 0, stream>>>(x, parent, tileCnt, tileList, dcol);
    bridge_k<<<(NE4 + 255) / 256, 256, 0, stream>>>(parent);
    select_k<<<BB, 256, 0, stream>>>(tileCnt, tileList, parent, ids);
    accum_k<<<BB * NT, 256, 0, stream>>>(parent, ids, dcol, drow);
    bbox_k<<<BB * KK, 384, 0, stream>>>(dcol, drow, out);
}